// Round 2
// baseline (472.625 us; speedup 1.0000x reference)
//
#include <hip/hip_runtime.h>
#include <hip/hip_bf16.h>

// Problem constants (fixed by setup_inputs)
#define NNODES 50000
#define NEDGES 800000
#define DIM    128
#define NRELS  4      // edge relations; weight slice 4 = self-loop

typedef __attribute__((ext_vector_type(8))) short bf16x8;  // 8 bf16 = 4 VGPRs
typedef __attribute__((ext_vector_type(8))) unsigned short u16x8;
typedef __attribute__((ext_vector_type(4))) float f32x4;

// ---- ws layout (bytes) ----
// agg keys  : u32[NNODES*DIM]                 @ 0          (25,600,000 B)
// eidx      : int[NEDGES+64]                  @ 25,600,000 ( 3,200,256 B)
// ctrl      : u32[16] cnt[4],cur[4],toff[5]   @ 28,800,256 (        64 B)
// Wt (W^T)  : bf16[5*128*128]                 @ 28,800,320 (   163,840 B)
// xbf       : bf16[NNODES*DIM]                @ 28,964,160 (12,800,000 B)
// total ~41.8 MB
#define EIDX_OFF 25600000
#define CTRL_OFF 28800256
#define WT_OFF   28800320
#define XBF_OFF  28964160

// monotonic float -> u32 key (order-preserving); key(any real) > 0, so 0 = "no edge"
__device__ __forceinline__ unsigned fkey(float f) {
  unsigned b = __float_as_uint(f);
  return (b & 0x80000000u) ? ~b : (b | 0x80000000u);
}
__device__ __forceinline__ float fval(unsigned k) {
  unsigned b = (k & 0x80000000u) ? (k ^ 0x80000000u) : ~k;
  return __uint_as_float(b);
}
__device__ __forceinline__ unsigned short f2bf(float f) {  // RNE f32->bf16
  unsigned u = __float_as_uint(f);
  return (unsigned short)((u + 0x7FFFu + ((u >> 16) & 1u)) >> 16);
}

// ---- init: zero agg keys, fill eidx with -1, zero ctrl ----
__global__ void k_init(unsigned* __restrict__ agg, int* __restrict__ eidx,
                       unsigned* __restrict__ ctrl) {
  int stride = gridDim.x * blockDim.x;
  for (int i = blockIdx.x * blockDim.x + threadIdx.x; i < NNODES * DIM; i += stride) {
    agg[i] = 0u;
    if (i < NEDGES + 64) eidx[i] = -1;
    if (i < 16) ctrl[i] = 0u;
  }
}

// ---- convert x f32 -> bf16 (8 elems/thread) ----
__global__ void k_conv(const float* __restrict__ x, unsigned short* __restrict__ xbf) {
  int i = blockIdx.x * blockDim.x + threadIdx.x;
  if (i < NNODES * DIM / 8) {
    const float4* p = (const float4*)x + i * 2;
    float4 v0 = p[0], v1 = p[1];
    u16x8 o;
    o[0] = f2bf(v0.x); o[1] = f2bf(v0.y); o[2] = f2bf(v0.z); o[3] = f2bf(v0.w);
    o[4] = f2bf(v1.x); o[5] = f2bf(v1.y); o[6] = f2bf(v1.z); o[7] = f2bf(v1.w);
    *(u16x8*)(xbf + i * 8) = o;
  }
}

// ---- histogram of rel ----
__global__ void k_hist(const int* __restrict__ rel, unsigned* __restrict__ ctrl) {
  __shared__ unsigned h[NRELS];
  if (threadIdx.x < NRELS) h[threadIdx.x] = 0u;
  __syncthreads();
  int stride = gridDim.x * blockDim.x;
  for (int e = blockIdx.x * blockDim.x + threadIdx.x; e < NEDGES; e += stride) {
    int r = rel[e];
    if (r < 0) r = 0;
    if (r >= NRELS) r = NRELS - 1;
    atomicAdd(&h[r], 1u);
  }
  __syncthreads();
  if (threadIdx.x < NRELS) atomicAdd(&ctrl[threadIdx.x], h[threadIdx.x]);
}

// ---- padded tile offsets per relation (tiles of 16 edges) ----
__global__ void k_off(unsigned* __restrict__ ctrl) {
  if (blockIdx.x == 0 && threadIdx.x == 0) {
    unsigned t = 0;
    for (int r = 0; r < NRELS; r++) {
      ctrl[8 + r] = t;
      t += (ctrl[r] + 15u) / 16u;
    }
    ctrl[8 + NRELS] = t;
  }
}

// ---- scatter edge ids into rel-grouped order ----
__global__ void k_scat(const int* __restrict__ rel, unsigned* __restrict__ ctrl,
                       int* __restrict__ eidx) {
  __shared__ unsigned h[NRELS];
  __shared__ unsigned base[NRELS];
  if (threadIdx.x < NRELS) h[threadIdx.x] = 0u;
  __syncthreads();
  int e = blockIdx.x * blockDim.x + threadIdx.x;
  int r = 0;
  unsigned loc = 0;
  bool valid = (e < NEDGES);
  if (valid) {
    r = rel[e];
    if (r < 0) r = 0;
    if (r >= NRELS) r = NRELS - 1;
    loc = atomicAdd(&h[r], 1u);
  }
  __syncthreads();
  if (threadIdx.x < NRELS) base[threadIdx.x] = atomicAdd(&ctrl[4 + threadIdx.x], h[threadIdx.x]);
  __syncthreads();
  if (valid) {
    unsigned pos = ctrl[8 + r] * 16u + base[r] + loc;
    eidx[pos] = e;
  }
}

// ---- transpose+convert weights: Wt[r][col][k] = bf16(W[r][k][col]) ----
__global__ void k_wt(const float* __restrict__ W, unsigned short* __restrict__ Wt) {
  int i = blockIdx.x * blockDim.x + threadIdx.x;
  if (i < 5 * DIM * DIM) {
    int r = i >> 14;
    int rem = i & 16383;
    int k = rem >> 7, c = rem & 127;
    Wt[(r << 14) + (c << 7) + k] = f2bf(W[i]);
  }
}

// ---- edge GEMM + atomic segment-max ----
// One wave per 16-edge tile (range-assigned so rel is piecewise-constant).
// B (W^T of current rel) held fully in registers: 8 col-tiles x 4 k-steps x 16B.
__global__ __launch_bounds__(256, 2) void k_edge(
    const unsigned short* __restrict__ x, const unsigned short* __restrict__ Wt,
    const float* __restrict__ bias, const int* __restrict__ src,
    const int* __restrict__ dst, const int* __restrict__ eidx,
    const unsigned* __restrict__ ctrl, unsigned* __restrict__ agg) {
  int lane = threadIdx.x & 63;
  int wid = blockIdx.x * (blockDim.x >> 6) + (threadIdx.x >> 6);
  int nw = gridDim.x * (blockDim.x >> 6);
  unsigned toff[5];
#pragma unroll
  for (int r = 0; r < 5; r++) toff[r] = ctrl[8 + r];
  int T = (int)toff[4];
  int tpw = (T + nw - 1) / nw;
  int t0 = wid * tpw, t1 = min(T, t0 + tpw);
  if (t0 >= t1) return;

  int col = lane & 15, quad = lane >> 4;
  bf16x8 bf[8][4];
  float bias_f[8];
  int rcur = -1;

  for (int t = t0; t < t1; ++t) {
    int r = 0;
    while (r < NRELS - 1 && (unsigned)t >= toff[r + 1]) r++;
    if (r != rcur) {
      rcur = r;
      const unsigned short* wr = Wt + (r << 14);
#pragma unroll
      for (int ct = 0; ct < 8; ct++) {
#pragma unroll
        for (int kk = 0; kk < 4; kk++)
          bf[ct][kk] = *(const bf16x8*)(wr + ((ct * 16 + col) << 7) + kk * 32 + quad * 8);
        bias_f[ct] = bias[(r << 7) + ct * 16 + col];
      }
    }
    // A fragments: row = lane&15, k = quad*8 + j (+ kk*32)
    int ea = eidx[t * 16 + col];
    int sa = (ea >= 0) ? src[ea] : 0;
    const unsigned short* xrow = x + (sa << 7);
    bf16x8 a[4];
#pragma unroll
    for (int kk = 0; kk < 4; kk++) a[kk] = *(const bf16x8*)(xrow + kk * 32 + quad * 8);

    // dst for the 4 C-rows this lane writes (rows quad*4+j)
    int dstw[4];
#pragma unroll
    for (int j = 0; j < 4; j++) {
      int er = eidx[t * 16 + quad * 4 + j];
      dstw[j] = (er >= 0) ? dst[er] : -1;
    }

#pragma unroll
    for (int ct = 0; ct < 8; ct++) {
      f32x4 acc = {0.f, 0.f, 0.f, 0.f};
#pragma unroll
      for (int kk = 0; kk < 4; kk++)
        acc = __builtin_amdgcn_mfma_f32_16x16x32_bf16(a[kk], bf[ct][kk], acc, 0, 0, 0);
#pragma unroll
      for (int j = 0; j < 4; j++) {
        if (dstw[j] >= 0) {
          float v = acc[j] + bias_f[ct];
          atomicMax(&agg[(dstw[j] << 7) + ct * 16 + col], fkey(v));
        }
      }
    }
  }
}

// ---- self-loop GEMM + combine with decoded max-agg, store f32 ----
__global__ __launch_bounds__(256, 2) void k_node(
    const unsigned short* __restrict__ x, const unsigned short* __restrict__ Wt,
    const float* __restrict__ bias, const unsigned* __restrict__ agg,
    float* __restrict__ out) {
  int lane = threadIdx.x & 63;
  int wid = blockIdx.x * (blockDim.x >> 6) + (threadIdx.x >> 6);
  int col = lane & 15, quad = lane >> 4;
  int row0 = wid * 16;
  if (row0 >= NNODES) return;

  const unsigned short* wr = Wt + (4 << 14);
  bf16x8 bf[8][4];
  float bias_f[8];
#pragma unroll
  for (int ct = 0; ct < 8; ct++) {
#pragma unroll
    for (int kk = 0; kk < 4; kk++)
      bf[ct][kk] = *(const bf16x8*)(wr + ((ct * 16 + col) << 7) + kk * 32 + quad * 8);
    bias_f[ct] = bias[(4 << 7) + ct * 16 + col];
  }
  int na = min(row0 + col, NNODES - 1);
  bf16x8 a[4];
#pragma unroll
  for (int kk = 0; kk < 4; kk++)
    a[kk] = *(const bf16x8*)(x + (na << 7) + kk * 32 + quad * 8);

#pragma unroll
  for (int ct = 0; ct < 8; ct++) {
    f32x4 acc = {0.f, 0.f, 0.f, 0.f};
#pragma unroll
    for (int kk = 0; kk < 4; kk++)
      acc = __builtin_amdgcn_mfma_f32_16x16x32_bf16(a[kk], bf[ct][kk], acc, 0, 0, 0);
#pragma unroll
    for (int j = 0; j < 4; j++) {
      int n = row0 + quad * 4 + j;
      if (n < NNODES) {
        unsigned k = agg[(n << 7) + ct * 16 + col];
        float av = (k == 0u) ? 0.f : fval(k);
        out[(n << 7) + ct * 16 + col] = acc[j] + bias_f[ct] + av;
      }
    }
  }
}

extern "C" void kernel_launch(void* const* d_in, const int* in_sizes, int n_in,
                              void* d_out, int out_size, void* d_ws, size_t ws_size,
                              hipStream_t stream) {
  const float* x = (const float*)d_in[0];
  const float* W = (const float*)d_in[1];
  const float* bias = (const float*)d_in[2];
  const int* src = (const int*)d_in[3];
  const int* dst = (const int*)d_in[4];
  const int* rel = (const int*)d_in[5];

  char* ws = (char*)d_ws;
  unsigned* agg = (unsigned*)ws;
  int* eidx = (int*)(ws + EIDX_OFF);
  unsigned* ctrl = (unsigned*)(ws + CTRL_OFF);
  unsigned short* Wt = (unsigned short*)(ws + WT_OFF);
  unsigned short* xbf = (unsigned short*)(ws + XBF_OFF);

  hipLaunchKernelGGL(k_init, dim3(4096), dim3(256), 0, stream, agg, eidx, ctrl);
  hipLaunchKernelGGL(k_conv, dim3((NNODES * DIM / 8 + 255) / 256), dim3(256), 0, stream, x, xbf);
  hipLaunchKernelGGL(k_hist, dim3(1024), dim3(256), 0, stream, rel, ctrl);
  hipLaunchKernelGGL(k_off, dim3(1), dim3(64), 0, stream, ctrl);
  hipLaunchKernelGGL(k_scat, dim3((NEDGES + 255) / 256), dim3(256), 0, stream, rel, ctrl, eidx);
  hipLaunchKernelGGL(k_wt, dim3((5 * DIM * DIM + 255) / 256), dim3(256), 0, stream, W, Wt);
  hipLaunchKernelGGL(k_edge, dim3(1024), dim3(256), 0, stream, xbf, Wt, bias, src, dst, eidx,
                     ctrl, agg);
  hipLaunchKernelGGL(k_node, dim3((NNODES / 16 + 3) / 4), dim3(256), 0, stream, xbf, Wt, bias,
                     agg, (float*)d_out);
}